// Round 10
// baseline (27.309 us; speedup 1.0000x reference)
//
#include <hip/hip_runtime.h>

// CTC batch cost, B=256 T=512 C=256 L=64 (S=129).
// R10 = R9 (producer/consumer wave split, counted-vmcnt producers, raw
// s_barrier rendezvous per 8-row group) + consumer-side double buffering:
// after barrier #g the consumer ISSUES ds_reads for group g but COMPUTES
// group g-1 from last iteration's registers, so LDS latency hides under the
// 8-step f64 compute (R9 lesson: ~180 ns/group of serial ds_read chain).
// Safety: the n->c register copy retires group-g reads before barrier #g+1,
// and the producer overwrites slot-group g%6 only after barrier #g+1.
// DP math: f64 linear domain, DPP wave shifts, log2-domain cut combine
// (verified absmax 0.0 in R6/R7/R8/R9).

constexpr int Bc = 256;
constexpr int Tc = 512;
constexpr int Cc = 256;
constexpr int Lc = 64;
constexpr int NS = 48;          // ring slots per direction = 6 groups x 8 rows

#define EPSF (1e-7f)
#define NEGF (-1e30f)

__device__ __forceinline__ float flog2(float x) {
    float r; asm("v_log_f32 %0, %1" : "=v"(r) : "v"(x)); return r;
}
__device__ __forceinline__ float fexp2(float x) {
    float r; asm("v_exp_f32 %0, %1" : "=v"(r) : "v"(x)); return r;
}
__device__ __forceinline__ float lse2(float a, float b) {
    float m = fmaxf(a, b);
    float d = fminf(a, b) - m;
    return m + flog2(1.f + fexp2(d));
}
// log2 of a positive double via exponent extraction + f32 mantissa log.
__device__ __forceinline__ float dlog2(double x) {
    if (!(x > 1e-300)) return NEGF;
    const int hb = __double2hiint(x);
    const int lb = __double2loint(x);
    const int e  = ((hb >> 20) & 0x7FF) - 1022;
    const double m = __hiloint2double((hb & 0x800FFFFF) | (1022 << 20), lb);
    return flog2((float)m) + (float)e;            // m in [0.5, 1)
}
// double wave shifts via paired 32-bit DPP; 'old' fills the boundary lane.
__device__ __forceinline__ double dpp_up1_d(double old, double src) {   // lane i <- i-1
    const int rl = __builtin_amdgcn_update_dpp(
        __double2loint(old), __double2loint(src), 0x138, 0xF, 0xF, false);
    const int rh = __builtin_amdgcn_update_dpp(
        __double2hiint(old), __double2hiint(src), 0x138, 0xF, 0xF, false);
    return __hiloint2double(rh, rl);
}
__device__ __forceinline__ double dpp_dn1_d(double old, double src) {   // lane i <- i+1
    const int rl = __builtin_amdgcn_update_dpp(
        __double2loint(old), __double2loint(src), 0x130, 0xF, 0xF, false);
    const int rh = __builtin_amdgcn_update_dpp(
        __double2hiint(old), __double2hiint(src), 0x130, 0xF, 0xF, false);
    return __hiloint2double(rh, rl);
}
// async global->LDS: lane l writes bytes [16l,16l+16) of the 1 KB slot.
__device__ __forceinline__ void stage16(const float* g, float* l) {
    __builtin_amdgcn_global_load_lds(
        (const __attribute__((address_space(1))) void*)g,
        (__attribute__((address_space(3))) void*)l, 16, 0, 0);
}

__global__ __launch_bounds__(256, 1) void ctc_fb_kernel(
        const int* __restrict__ y_true,
        const float* __restrict__ y_pred,
        float* __restrict__ out)
{
    const int b    = blockIdx.x;
    const int lane = threadIdx.x & 63;
    const int wid  = threadIdx.x >> 6;
    const int dir  = wid & 1;

    __shared__ float ring[2][NS][Cc];       // 96 KB
    __shared__ float Cl[64], Ch[64];
    __shared__ float CexS;

    const float* __restrict__ bbase = y_pred + (size_t)b * Tc * Cc;

    double lo = 0.0, hi = 0.0, ex = 0.0;

    if (wid >= 2) {
        // ---------------- producer wave for direction 'dir' ----------------
        // (identical to R9) local row u -> global row: fwd u, bwd 511-u.
        const float* __restrict__ g0 =
            dir ? (bbase + (size_t)(Tc - 1) * Cc + lane * 4)
                : (bbase + lane * 4);
        const ptrdiff_t stp = dir ? -(ptrdiff_t)Cc : (ptrdiff_t)Cc;
        float* const lds0 = &ring[dir][0][0];
        #pragma unroll
        for (int u = 0; u < 32; ++u)
            stage16(g0 + stp * u, lds0 + u * Cc);
        int sg = 32;                         // slot offset of group g+4
        for (int g = 0; g < 32; ++g) {
            if (g <= 27) {                   // stage group g+4 (rows 8g+32..39)
                const float* gb = g0 + stp * (8 * (g + 4));
                float* lb = lds0 + sg * Cc;
                #pragma unroll
                for (int j = 0; j < 8; ++j)
                    stage16(gb + stp * j, lb + j * Cc);
            }
            if (g <= 27)      asm volatile("s_waitcnt vmcnt(32)" ::: "memory");
            else if (g == 28) asm volatile("s_waitcnt vmcnt(24)" ::: "memory");
            else if (g == 29) asm volatile("s_waitcnt vmcnt(16)" ::: "memory");
            else if (g == 30) asm volatile("s_waitcnt vmcnt(8)"  ::: "memory");
            else              asm volatile("s_waitcnt vmcnt(0)"  ::: "memory");
            __builtin_amdgcn_s_barrier();    // rendezvous #g (raw: no drain)
            sg += 8; if (sg >= NS) sg = 0;
        }
    } else {
        // ---------------- consumer (DP) waves ----------------
        const int lab  = y_true[b * Lc + lane];
        const int labp = __shfl_up(lab, 1);
        const int labn = __shfl_down(lab, 1);

        float cB0, cB1, cB2, cB3, cB4, cB5, cB6, cB7;
        float cL0, cL1, cL2, cL3, cL4, cL5, cL6, cL7;

        if (wid == 0) {
            const bool allowF = (lane >= 1) && (lab != labp);
            auto stepF = [&](float pBf, float pLf) {
                const double pB = (double)pBf, pL = (double)pLf;
                const double prevHi = dpp_up1_d(0.0, hi);
                const double sk  = allowF ? prevHi : 0.0;
                const double nlo = (lo + prevHi) * pB;
                const double nhi = (hi + lo + sk) * pL;
                ex = (ex + hi) * pB;     // real only at lane 63 (127->128)
                hi = nhi; lo = nlo;
            };
            asm volatile("" ::: "memory");
            __builtin_amdgcn_s_barrier();            // #0: group 0 ready
            asm volatile("" ::: "memory");
#define RDC(j) { cL##j = ring[0][j][lab] + EPSF; cB##j = ring[0][j][Cc - 1] + EPSF; }
            RDC(0) RDC(1) RDC(2) RDC(3) RDC(4) RDC(5) RDC(6) RDC(7)
#undef RDC
            int sbn = 8;
            for (int g = 1; g < 32; ++g) {
                asm volatile("" ::: "memory");
                __builtin_amdgcn_s_barrier();        // #g: group g ready
                asm volatile("" ::: "memory");
#define RDN(j) const float nL##j = ring[0][sbn + j][lab] + EPSF, \
                           nB##j = ring[0][sbn + j][Cc - 1] + EPSF;
                RDN(0) RDN(1) RDN(2) RDN(3) RDN(4) RDN(5) RDN(6) RDN(7)
#undef RDN
                // compute group g-1 (registers) while group-g reads fly
                if (g == 1) {
                    lo = (lane == 0) ? (double)cB0 : 0.0;    // alpha0(0)
                    hi = (lane == 0) ? (double)cL0 : 0.0;    // alpha0(1)
                } else stepF(cB0, cL0);
                stepF(cB1, cL1); stepF(cB2, cL2); stepF(cB3, cL3);
                stepF(cB4, cL4); stepF(cB5, cL5); stepF(cB6, cL6);
                stepF(cB7, cL7);
                cB0 = nB0; cB1 = nB1; cB2 = nB2; cB3 = nB3;
                cB4 = nB4; cB5 = nB5; cB6 = nB6; cB7 = nB7;
                cL0 = nL0; cL1 = nL1; cL2 = nL2; cL3 = nL3;
                cL4 = nL4; cL5 = nL5; cL6 = nL6; cL7 = nL7;
                sbn += 8; if (sbn >= NS) sbn = 0;
            }
            // group 31
            stepF(cB0, cL0); stepF(cB1, cL1); stepF(cB2, cL2); stepF(cB3, cL3);
            stepF(cB4, cL4); stepF(cB5, cL5); stepF(cB6, cL6); stepF(cB7, cL7);
        } else {
            const bool allowB = (lane < 63) && (labn != lab);
            auto stepB = [&](float pBf, float pLf) {
                const double pB = (double)pBf, pL = (double)pLf;
                const double nlo_s = dpp_dn1_d(ex, lo);   // B(2l+2); l63 <- ex
                const double nhi_s = dpp_dn1_d(0.0, hi);  // B(2l+3); l63 <- 0
                const double sk = allowB ? nhi_s : 0.0;
                const double l2 = (lo + hi) * pB;
                const double h2 = (hi + nlo_s + sk) * pL;
                ex = ex * pB;
                lo = l2; hi = h2;
            };
            asm volatile("" ::: "memory");
            __builtin_amdgcn_s_barrier();            // #0: group 0 ready
            asm volatile("" ::: "memory");
#define RDC(j) { cL##j = ring[1][j][lab] + EPSF; cB##j = ring[1][j][Cc - 1] + EPSF; }
            RDC(0) RDC(1) RDC(2) RDC(3) RDC(4) RDC(5) RDC(6) RDC(7)
#undef RDC
            int sbn = 8;
            for (int g = 1; g < 32; ++g) {
                asm volatile("" ::: "memory");
                __builtin_amdgcn_s_barrier();        // #g: group g ready
                asm volatile("" ::: "memory");
#define RDN(j) const float nL##j = ring[1][sbn + j][lab] + EPSF, \
                           nB##j = ring[1][sbn + j][Cc - 1] + EPSF;
                RDN(0) RDN(1) RDN(2) RDN(3) RDN(4) RDN(5) RDN(6) RDN(7)
#undef RDN
                if (g == 1) {
                    ex = (double)cB0;                          // beta511(128)
                    hi = (lane == 63) ? (double)cL0 : 0.0;     // beta511(127)
                    lo = 0.0;
                } else stepB(cB0, cL0);
                stepB(cB1, cL1); stepB(cB2, cL2); stepB(cB3, cL3);
                stepB(cB4, cL4); stepB(cB5, cL5); stepB(cB6, cL6);
                stepB(cB7, cL7);
                cB0 = nB0; cB1 = nB1; cB2 = nB2; cB3 = nB3;
                cB4 = nB4; cB5 = nB5; cB6 = nB6; cB7 = nB7;
                cL0 = nL0; cL1 = nL1; cL2 = nL2; cL3 = nL3;
                cL4 = nL4; cL5 = nL5; cL6 = nL6; cL7 = nL7;
                sbn += 8; if (sbn >= NS) sbn = 0;
            }
            stepB(cB0, cL0); stepB(cB1, cL1); stepB(cB2, cL2); stepB(cB3, cL3);
            stepB(cB4, cL4); stepB(cB5, cL5); stepB(cB6, cL6); stepB(cB7, cL7);
            // cut combine half-step: C(s) = B(s) + B(s+1) + allowB(s)*B(s+2)
            const double nlo_s = dpp_dn1_d(ex, lo);
            const double nhi_s = dpp_dn1_d(0.0, hi);
            const double sk = allowB ? nhi_s : 0.0;
            Cl[lane] = dlog2(lo + hi);
            Ch[lane] = dlog2(hi + nlo_s + sk);
            if (lane == 63) CexS = dlog2(ex);
        }
    }

    __syncthreads();

    if (wid == 0) {
        const float w1 = dlog2(lo) + Cl[lane];
        const float w2 = dlog2(hi) + Ch[lane];
        float w = lse2(w1, w2);
        if (lane == 63) w = lse2(w, dlog2(ex) + CexS);
        #pragma unroll
        for (int off = 32; off; off >>= 1) w = lse2(w, __shfl_xor(w, off));
        if (lane == 0)
            out[b] = -0.69314718055994530942f * w;     // ln2 * log2 -> ln
    }
}

extern "C" void kernel_launch(void* const* d_in, const int* in_sizes, int n_in,
                              void* d_out, int out_size, void* d_ws, size_t ws_size,
                              hipStream_t stream) {
    const int*   y_true = (const int*)d_in[0];
    const float* y_pred = (const float*)d_in[1];
    float*       out    = (float*)d_out;
    ctc_fb_kernel<<<dim3(Bc), dim3(256), 0, stream>>>(y_true, y_pred, out);
}

// Round 11
// 26.415 us; speedup vs baseline: 1.0338x; 1.0338x over previous
//
#include <hip/hip_runtime.h>

// CTC batch cost, B=256 T=512 C=256 L=64 (S=129).
// R11 = R9 (producer/consumer wave split, counted-vmcnt producers, raw
// s_barrier rendezvous per 8-row group, consumer computes immediately after
// its reads) with TWO producer waves per direction (6 waves/block total):
// each 8-row group is staged half by producer A (rows 0-3) and half by
// producer B (rows 4-7). Per-wave vmcnt counting (16 steady = 4 groups x 4
// loads ahead). R10 lesson: consumer-side double-buffering was neutral ->
// the residual is delivery-side memory parallelism, so double the VMEM-
// issuing waves per CU. DP math: f64 linear domain, DPP wave shifts,
// log2-domain cut combine (absmax 0.0 in R6-R10).

constexpr int Bc = 256;
constexpr int Tc = 512;
constexpr int Cc = 256;
constexpr int Lc = 64;
constexpr int NS = 48;          // ring slots per direction = 6 groups x 8 rows

#define EPSF (1e-7f)
#define NEGF (-1e30f)

__device__ __forceinline__ float flog2(float x) {
    float r; asm("v_log_f32 %0, %1" : "=v"(r) : "v"(x)); return r;
}
__device__ __forceinline__ float fexp2(float x) {
    float r; asm("v_exp_f32 %0, %1" : "=v"(r) : "v"(x)); return r;
}
__device__ __forceinline__ float lse2(float a, float b) {
    float m = fmaxf(a, b);
    float d = fminf(a, b) - m;
    return m + flog2(1.f + fexp2(d));
}
// log2 of a positive double via exponent extraction + f32 mantissa log.
__device__ __forceinline__ float dlog2(double x) {
    if (!(x > 1e-300)) return NEGF;
    const int hb = __double2hiint(x);
    const int lb = __double2loint(x);
    const int e  = ((hb >> 20) & 0x7FF) - 1022;
    const double m = __hiloint2double((hb & 0x800FFFFF) | (1022 << 20), lb);
    return flog2((float)m) + (float)e;            // m in [0.5, 1)
}
// double wave shifts via paired 32-bit DPP; 'old' fills the boundary lane.
__device__ __forceinline__ double dpp_up1_d(double old, double src) {   // lane i <- i-1
    const int rl = __builtin_amdgcn_update_dpp(
        __double2loint(old), __double2loint(src), 0x138, 0xF, 0xF, false);
    const int rh = __builtin_amdgcn_update_dpp(
        __double2hiint(old), __double2hiint(src), 0x138, 0xF, 0xF, false);
    return __hiloint2double(rh, rl);
}
__device__ __forceinline__ double dpp_dn1_d(double old, double src) {   // lane i <- i+1
    const int rl = __builtin_amdgcn_update_dpp(
        __double2loint(old), __double2loint(src), 0x130, 0xF, 0xF, false);
    const int rh = __builtin_amdgcn_update_dpp(
        __double2hiint(old), __double2hiint(src), 0x130, 0xF, 0xF, false);
    return __hiloint2double(rh, rl);
}
// async global->LDS: lane l writes bytes [16l,16l+16) of the 1 KB slot.
__device__ __forceinline__ void stage16(const float* g, float* l) {
    __builtin_amdgcn_global_load_lds(
        (const __attribute__((address_space(1))) void*)g,
        (__attribute__((address_space(3))) void*)l, 16, 0, 0);
}

__global__ __launch_bounds__(384, 1) void ctc_fb_kernel(
        const int* __restrict__ y_true,
        const float* __restrict__ y_pred,
        float* __restrict__ out)
{
    const int b    = blockIdx.x;
    const int lane = threadIdx.x & 63;
    const int wid  = threadIdx.x >> 6;

    __shared__ float ring[2][NS][Cc];       // 96 KB
    __shared__ float Cl[64], Ch[64];
    __shared__ float CexS;

    const float* __restrict__ bbase = y_pred + (size_t)b * Tc * Cc;

    double lo = 0.0, hi = 0.0, ex = 0.0;

    if (wid >= 2) {
        // ------------- producer waves: wid-2 = {fwd0, bwd0, fwd1, bwd1} ----
        const int pid  = wid - 2;
        const int dir  = pid & 1;
        const int half = pid >> 1;           // which 4-row half of each group
        // local row u -> global row: fwd u, bwd 511-u.
        const float* __restrict__ g0 =
            dir ? (bbase + (size_t)(Tc - 1) * Cc + lane * 4)
                : (bbase + lane * 4);
        const ptrdiff_t stp = dir ? -(ptrdiff_t)Cc : (ptrdiff_t)Cc;
        float* const lds0 = &ring[dir][0][0];
        // prologue: this half's rows of groups 0..3 (16 loads)
        #pragma unroll
        for (int G = 0; G < 4; ++G) {
            #pragma unroll
            for (int j = 0; j < 4; ++j) {
                const int u = 8 * G + 4 * half + j;
                stage16(g0 + stp * u, lds0 + u * Cc);
            }
        }
        int sg = 32;                         // slot base of group g+4
        for (int g = 0; g < 32; ++g) {
            if (g <= 27) {                   // stage this half of group g+4
                const float* gb = g0 + stp * (8 * (g + 4) + 4 * half);
                float* lb = lds0 + (sg + 4 * half) * Cc;
                #pragma unroll
                for (int j = 0; j < 4; ++j)
                    stage16(gb + stp * j, lb + j * Cc);
            }
            // per-wave counting: issued 16+4(g+1) by end of iter g (g<=27);
            // group g's 4 loads must be retired -> vmcnt(16) steady.
            if (g <= 27)      asm volatile("s_waitcnt vmcnt(16)" ::: "memory");
            else if (g == 28) asm volatile("s_waitcnt vmcnt(12)" ::: "memory");
            else if (g == 29) asm volatile("s_waitcnt vmcnt(8)"  ::: "memory");
            else if (g == 30) asm volatile("s_waitcnt vmcnt(4)"  ::: "memory");
            else              asm volatile("s_waitcnt vmcnt(0)"  ::: "memory");
            __builtin_amdgcn_s_barrier();    // rendezvous #g (raw: no drain)
            sg += 8; if (sg >= NS) sg = 0;
        }
    } else {
        // ---------------- consumer (DP) waves (R9 form) ----------------
        const int lab  = y_true[b * Lc + lane];
        const int labp = __shfl_up(lab, 1);
        const int labn = __shfl_down(lab, 1);

        if (wid == 0) {
            // forward DP: steps/rows 0..255
            const bool allowF = (lane >= 1) && (lab != labp);
            auto stepF = [&](float pBf, float pLf) {
                const double pB = (double)pBf, pL = (double)pLf;
                const double prevHi = dpp_up1_d(0.0, hi);
                const double sk  = allowF ? prevHi : 0.0;
                const double nlo = (lo + prevHi) * pB;
                const double nhi = (hi + lo + sk) * pL;
                ex = (ex + hi) * pB;     // real only at lane 63 (127->128)
                hi = nhi; lo = nlo;
            };
            int sb = 0;
            for (int g = 0; g < 32; ++g) {
                asm volatile("" ::: "memory");
                __builtin_amdgcn_s_barrier();        // group g ready
                asm volatile("" ::: "memory");
#define RDF(j) const float cL##j = ring[0][sb + j][lab] + EPSF, \
                           cB##j = ring[0][sb + j][Cc - 1] + EPSF;
                RDF(0) RDF(1) RDF(2) RDF(3) RDF(4) RDF(5) RDF(6) RDF(7)
#undef RDF
                if (g == 0) {
                    lo = (lane == 0) ? (double)cB0 : 0.0;    // alpha0(0)
                    hi = (lane == 0) ? (double)cL0 : 0.0;    // alpha0(1)
                } else stepF(cB0, cL0);
                stepF(cB1, cL1); stepF(cB2, cL2); stepF(cB3, cL3);
                stepF(cB4, cL4); stepF(cB5, cL5); stepF(cB6, cL6);
                stepF(cB7, cL7);
                sb += 8; if (sb >= NS) sb = 0;
            }
        } else {
            // backward DP: local rows 0..255 <-> t = 511..256
            const bool allowB = (lane < 63) && (labn != lab);
            auto stepB = [&](float pBf, float pLf) {
                const double pB = (double)pBf, pL = (double)pLf;
                const double nlo_s = dpp_dn1_d(ex, lo);   // B(2l+2); l63 <- ex
                const double nhi_s = dpp_dn1_d(0.0, hi);  // B(2l+3); l63 <- 0
                const double sk = allowB ? nhi_s : 0.0;
                const double l2 = (lo + hi) * pB;
                const double h2 = (hi + nlo_s + sk) * pL;
                ex = ex * pB;
                lo = l2; hi = h2;
            };
            int sb = 0;
            for (int g = 0; g < 32; ++g) {
                asm volatile("" ::: "memory");
                __builtin_amdgcn_s_barrier();        // group g ready
                asm volatile("" ::: "memory");
#define RDB(j) const float cL##j = ring[1][sb + j][lab] + EPSF, \
                           cB##j = ring[1][sb + j][Cc - 1] + EPSF;
                RDB(0) RDB(1) RDB(2) RDB(3) RDB(4) RDB(5) RDB(6) RDB(7)
#undef RDB
                if (g == 0) {
                    ex = (double)cB0;                          // beta511(128)
                    hi = (lane == 63) ? (double)cL0 : 0.0;     // beta511(127)
                    lo = 0.0;
                } else stepB(cB0, cL0);
                stepB(cB1, cL1); stepB(cB2, cL2); stepB(cB3, cL3);
                stepB(cB4, cL4); stepB(cB5, cL5); stepB(cB6, cL6);
                stepB(cB7, cL7);
                sb += 8; if (sb >= NS) sb = 0;
            }
            // cut combine half-step: C(s) = B(s) + B(s+1) + allowB(s)*B(s+2),
            // stored log2-domain (R4 lesson: anti-aligned maxima).
            const double nlo_s = dpp_dn1_d(ex, lo);
            const double nhi_s = dpp_dn1_d(0.0, hi);
            const double sk = allowB ? nhi_s : 0.0;
            Cl[lane] = dlog2(lo + hi);
            Ch[lane] = dlog2(hi + nlo_s + sk);
            if (lane == 63) CexS = dlog2(ex);
        }
    }

    __syncthreads();

    if (wid == 0) {
        const float w1 = dlog2(lo) + Cl[lane];
        const float w2 = dlog2(hi) + Ch[lane];
        float w = lse2(w1, w2);
        if (lane == 63) w = lse2(w, dlog2(ex) + CexS);
        #pragma unroll
        for (int off = 32; off; off >>= 1) w = lse2(w, __shfl_xor(w, off));
        if (lane == 0)
            out[b] = -0.69314718055994530942f * w;     // ln2 * log2 -> ln
    }
}

extern "C" void kernel_launch(void* const* d_in, const int* in_sizes, int n_in,
                              void* d_out, int out_size, void* d_ws, size_t ws_size,
                              hipStream_t stream) {
    const int*   y_true = (const int*)d_in[0];
    const float* y_pred = (const float*)d_in[1];
    float*       out    = (float*)d_out;
    ctc_fb_kernel<<<dim3(Bc), dim3(384), 0, stream>>>(y_true, y_pred, out);
}